// Round 1
// baseline (279.784 us; speedup 1.0000x reference)
//
#include <hip/hip_runtime.h>

// CRF loss: S=512, B=256, L=128.
// out = log_z - gold
//   gold = sum_t emit[t,b,y_t] + sum_t T[y_{t-1}, y_t]  (y_{-1} = start_id)
//   log_z via forward algorithm, fwd_0 = emit[0].
//
// Strategy: one block per batch (256 blocks = 256 CUs). Per step the
// log-semiring matvec is converted to a plain fp32 matvec on unnormalized
// weights w = 2^(fwd*log2e - ls2) against E = exp(T) (precomputed into
// registers: thread (j, half) holds E[64h..64h+64)[j] = 64 VGPRs).
// Renormalize by power-of-2 (exponent extraction, integer log-scale) every
// 4 steps. emit loads are prefetched 4-8 steps ahead (independent of scan).

#define LOG2E 1.4426950408889634f
#define LN2F  0.6931471805599453f

// One forward step. EMV = prefetched emit[t,b,j] (valid in h==0 threads).
// T_IDX = t. RENORM = compile-time 0/1.
#define CRF_STEP(EMV, T_IDX, RENORM) do {                                    \
    float s0 = 0.f, s1 = 0.f, s2 = 0.f, s3 = 0.f;                            \
    const float4* w4p = (const float4*)(w_lds + ibase);                      \
    _Pragma("unroll")                                                        \
    for (int q = 0; q < 16; ++q) {                                           \
        float4 w4 = w4p[q];                                                  \
        s0 = fmaf(w4.x, e_reg[4*q+0], s0);                                   \
        s1 = fmaf(w4.y, e_reg[4*q+1], s1);                                   \
        s2 = fmaf(w4.z, e_reg[4*q+2], s2);                                   \
        s3 = fmaf(w4.w, e_reg[4*q+3], s3);                                   \
    }                                                                        \
    float ssum = (s0 + s1) + (s2 + s3);                                      \
    if (h == 1) part_lds[j] = ssum;                                          \
    __syncthreads();                                                         \
    if (h == 0) {                                                            \
        float tot = ssum + part_lds[j];                                      \
        nw = tot * exp2f((EMV) * LOG2E);                                     \
        gold += (lab_lds[T_IDX] == j) ? (EMV) : 0.0f;                        \
        if (!(RENORM)) {                                                     \
            w_lds[j] = nw;                                                   \
        } else {                                                             \
            float m = nw;                                                    \
            _Pragma("unroll")                                                \
            for (int off = 32; off; off >>= 1)                               \
                m = fmaxf(m, __shfl_xor(m, off));                            \
            if ((tid & 63) == 0) red_lds[tid >> 6] = m;                      \
        }                                                                    \
    }                                                                        \
    __syncthreads();                                                         \
    if (RENORM) {                                                            \
        if (h == 0) {                                                        \
            float m = fmaxf(red_lds[0], red_lds[1]);                         \
            int me = ((__float_as_int(m) >> 23) & 0xFF) - 127;               \
            float scale = __int_as_float((127 - me) << 23);                  \
            nw *= scale;                                                     \
            ls2 += me;                                                       \
            w_lds[j] = nw;                                                   \
        }                                                                    \
        __syncthreads();                                                     \
    }                                                                        \
} while (0)

__global__ __launch_bounds__(256) void crf_forward_kernel(
    const float* __restrict__ emit,    // (512, 256, 128)
    const float* __restrict__ Tm,      // (128, 128)
    const int*   __restrict__ labels,  // (256, 512)
    const int*   __restrict__ start_p, // scalar
    float*       __restrict__ partials)// (256)
{
    const int b     = blockIdx.x;
    const int tid   = threadIdx.x;
    const int j     = tid & 127;
    const int h     = tid >> 7;     // which half of the i-sum this thread owns
    const int ibase = h << 6;

    __shared__ __align__(16) float w_lds[128];
    __shared__ float part_lds[128];
    __shared__ int   lab_lds[512];
    __shared__ float red_lds[8];

    // labels row -> LDS
    lab_lds[tid]       = labels[b * 512 + tid];
    lab_lds[tid + 256] = labels[b * 512 + tid + 256];

    // E column-half into registers: E[ibase+ii][j] = exp(T[ibase+ii][j])
    float e_reg[64];
#pragma unroll
    for (int ii = 0; ii < 64; ++ii)
        e_reg[ii] = exp2f(Tm[(ibase + ii) * 128 + j] * LOG2E);

    __syncthreads();

    // gold transition score: each thread handles t = tid and t = tid+256
    float gold = 0.0f;
    {
        const int start_id = start_p[0];
        int prev0 = (tid == 0) ? start_id : lab_lds[tid - 1];
        gold += Tm[prev0 * 128 + lab_lds[tid]];
        gold += Tm[lab_lds[tid + 255] * 128 + lab_lds[tid + 256]];
    }

    const float* emit_bj = emit + (size_t)b * 128 + j;  // stride per t: 32768

    // t = 0 init: fwd_0 = emit[0]
    float nw  = 0.0f;
    int   ls2 = 0;
    {
        float e0 = emit_bj[0];
        nw = exp2f(e0 * LOG2E);
        if (h == 0) {
            w_lds[j] = nw;
            gold += (lab_lds[0] == j) ? e0 : 0.0f;
        }
    }
    __syncthreads();

    // prefetch emit for t = 1..4
    float emA0 = 0.f, emA1 = 0.f, emA2 = 0.f, emA3 = 0.f;
    if (h == 0) {
        emA0 = emit_bj[(size_t)1 * 32768];
        emA1 = emit_bj[(size_t)2 * 32768];
        emA2 = emit_bj[(size_t)3 * 32768];
        emA3 = emit_bj[(size_t)4 * 32768];
    }

    // main loop: t = 1..508 in 127 groups of 4, renorm on 4th step of group
#pragma unroll 1
    for (int g = 0; g < 127; ++g) {
        const int tb = 4 * g + 1;
        float emB0 = 0.f, emB1 = 0.f, emB2 = 0.f, emB3 = 0.f;
        if (h == 0) {
            emB0 = emit_bj[(size_t)(tb + 4) * 32768];
            emB1 = emit_bj[(size_t)(tb + 5) * 32768];
            emB2 = emit_bj[(size_t)(tb + 6) * 32768];
            int t7 = tb + 7; if (t7 > 511) t7 = 511;   // clamp last prefetch
            emB3 = emit_bj[(size_t)t7 * 32768];
        }
        CRF_STEP(emA0, tb + 0, 0);
        CRF_STEP(emA1, tb + 1, 0);
        CRF_STEP(emA2, tb + 2, 0);
        CRF_STEP(emA3, tb + 3, 1);
        emA0 = emB0; emA1 = emB1; emA2 = emB2; emA3 = emB3;
    }
    // tail: t = 509, 510, 511 (no renorm needed; growth fits fp32)
    CRF_STEP(emA0, 509, 0);
    CRF_STEP(emA1, 510, 0);
    CRF_STEP(emA2, 511, 0);

    // final: log_z_b = (ls2 + log2(sum_j w[j])) * ln2 ; partial = lz - gold
    float sw = (h == 0) ? nw : 0.0f;
#pragma unroll
    for (int off = 32; off; off >>= 1) {
        sw   += __shfl_xor(sw, off);
        gold += __shfl_xor(gold, off);
    }
    __syncthreads();  // red_lds reuse
    const int wid = tid >> 6;
    if ((tid & 63) == 0) { red_lds[wid] = sw; red_lds[4 + wid] = gold; }
    __syncthreads();
    if (tid == 0) {
        float sum_w    = red_lds[0] + red_lds[1];        // waves 2,3 added 0
        float gold_tot = red_lds[4] + red_lds[5] + red_lds[6] + red_lds[7];
        float lz = ((float)ls2 + log2f(sum_w)) * LN2F;
        partials[b] = lz - gold_tot;
    }
}

__global__ __launch_bounds__(256) void crf_reduce_kernel(
    const float* __restrict__ partials, float* __restrict__ out)
{
    const int tid = threadIdx.x;
    float v = partials[tid];
#pragma unroll
    for (int off = 32; off; off >>= 1) v += __shfl_xor(v, off);
    __shared__ float r[4];
    if ((tid & 63) == 0) r[tid >> 6] = v;
    __syncthreads();
    if (tid == 0) out[0] = r[0] + r[1] + r[2] + r[3];
}

extern "C" void kernel_launch(void* const* d_in, const int* in_sizes, int n_in,
                              void* d_out, int out_size, void* d_ws, size_t ws_size,
                              hipStream_t stream) {
    const float* emit   = (const float*)d_in[0];
    const float* Tm     = (const float*)d_in[1];
    const int*   labels = (const int*)d_in[2];
    const int*   startp = (const int*)d_in[3];
    float* partials = (float*)d_ws;

    crf_forward_kernel<<<256, 256, 0, stream>>>(emit, Tm, labels, startp, partials);
    crf_reduce_kernel<<<1, 256, 0, stream>>>(partials, (float*)d_out);
}

// Round 2
// 259.281 us; speedup vs baseline: 1.0791x; 1.0791x over previous
//
#include <hip/hip_runtime.h>

// CRF loss, S=512, B=256, L=128, out = sum_b log_z_b - gold.
//
// Scan step as MFMA mini-GEMM per batch-group of 16:
//   D[j][b] = sum_i Et[j][i] * Wt[i][b],  Et = exp(T)^T (bf16, constant, in regs)
//   w_new[b][j] = D[j][b] * exp(emit[t][b][j]) * 2^{-renorm}
// 16 blocks (batch groups) x 256 threads (4 waves; wave w owns j in [32w,32w+32)).
// W lives in LDS as bf16 [16][128], double-buffered, 16B-block XOR swizzle
// (blk ^ (b&7)) so B-fragment ds_read_b128 is ~conflict-free.
// Renorm by power-of-2 exponent every 4 steps (exact scaling, int ls2).
// emit prefetched 4 steps ahead (2 x dwordx4 per lane per step).

#define LOG2E 1.4426950408889634f
#define LN2F  0.6931471805599453f

typedef float        f32x4 __attribute__((ext_vector_type(4)));
typedef unsigned int u32x4 __attribute__((ext_vector_type(4)));

__device__ __forceinline__ unsigned f2bf(float a) {
    unsigned ua = __float_as_uint(a);
    return (ua + 0x7FFFu + ((ua >> 16) & 1u)) >> 16;   // RNE to bf16
}
__device__ __forceinline__ unsigned pack2bf(float a, float b) {
    return f2bf(a) | (f2bf(b) << 16);
}

// Inline-asm MFMA (gfx950 unified VGPR file: v[] operands valid).
// FIRST: s_nop 1 covers VALU(zero-init)->MFMA SrcC hazard.
// FENCE: 16 nop cycles cover MFMA DstD -> VALU read hazard (4-pass MFMA ~11).
#define MFMA_FIRST(acc, a, b) \
    asm("s_nop 1\n\tv_mfma_f32_16x16x32_bf16 %0, %1, %2, %0" : "+v"(acc) : "v"(a), "v"(b))
#define MFMA_NEXT(acc, a, b) \
    asm("v_mfma_f32_16x16x32_bf16 %0, %1, %2, %0" : "+v"(acc) : "v"(a), "v"(b))
#define MFMA_FENCE(acc0, acc1) \
    asm("s_nop 7\n\ts_nop 7" : "+v"(acc0), "+v"(acc1))

// One scan step. XF0/XF1: prefetched emit float4 for tiles mt0/mt1.
// WSRC/WDST: char* LDS buffers. RN: compile-time renorm flag.
#define CRF_STEP(XF0, XF1, WSRC, WDST, RN) do {                               \
    u32x4 bq0 = *(const u32x4*)((WSRC) + roff0);                              \
    u32x4 bq1 = *(const u32x4*)((WSRC) + roff1);                              \
    u32x4 bq2 = *(const u32x4*)((WSRC) + roff2);                              \
    u32x4 bq3 = *(const u32x4*)((WSRC) + roff3);                              \
    float xs0 = __builtin_amdgcn_exp2f((XF0).x * LOG2E);                      \
    float xs1 = __builtin_amdgcn_exp2f((XF0).y * LOG2E);                      \
    float xs2 = __builtin_amdgcn_exp2f((XF0).z * LOG2E);                      \
    float xs3 = __builtin_amdgcn_exp2f((XF0).w * LOG2E);                      \
    float xs4 = __builtin_amdgcn_exp2f((XF1).x * LOG2E);                      \
    float xs5 = __builtin_amdgcn_exp2f((XF1).y * LOG2E);                      \
    float xs6 = __builtin_amdgcn_exp2f((XF1).z * LOG2E);                      \
    float xs7 = __builtin_amdgcn_exp2f((XF1).w * LOG2E);                      \
    f32x4 acc0 = {0.f, 0.f, 0.f, 0.f};                                        \
    f32x4 acc1 = {0.f, 0.f, 0.f, 0.f};                                        \
    MFMA_FIRST(acc0, af00, bq0);                                              \
    MFMA_NEXT (acc0, af01, bq1);                                              \
    MFMA_NEXT (acc0, af02, bq2);                                              \
    MFMA_NEXT (acc0, af03, bq3);                                              \
    MFMA_FIRST(acc1, af10, bq0);                                              \
    MFMA_NEXT (acc1, af11, bq1);                                              \
    MFMA_NEXT (acc1, af12, bq2);                                              \
    MFMA_NEXT (acc1, af13, bq3);                                              \
    MFMA_FENCE(acc0, acc1);                                                   \
    vv0 = acc0[0] * xs0; vv1 = acc0[1] * xs1;                                 \
    vv2 = acc0[2] * xs2; vv3 = acc0[3] * xs3;                                 \
    vv4 = acc1[0] * xs4; vv5 = acc1[1] * xs5;                                 \
    vv6 = acc1[2] * xs6; vv7 = acc1[3] * xs7;                                 \
    if (RN) {                                                                 \
        float mx = fmaxf(fmaxf(fmaxf(vv0, vv1), fmaxf(vv2, vv3)),             \
                         fmaxf(fmaxf(vv4, vv5), fmaxf(vv6, vv7)));            \
        mx = fmaxf(mx, __shfl_xor(mx, 1));                                    \
        mx = fmaxf(mx, __shfl_xor(mx, 2));                                    \
        mx = fmaxf(mx, __shfl_xor(mx, 4));                                    \
        mx = fmaxf(mx, __shfl_xor(mx, 8));                                    \
        mx = fmaxf(mx, __shfl_xor(mx, 16));                                   \
        mx = fmaxf(mx, __shfl_xor(mx, 32));                                   \
        if (l == 0) red[w] = mx;                                              \
        __syncthreads();                                                      \
        float gm = fmaxf(fmaxf(red[0], red[1]), fmaxf(red[2], red[3]));       \
        int Ee = (__float_as_int(gm) >> 23) & 0xFF;                           \
        ls2 += Ee - 127;                                                      \
        float scl = __int_as_float((int)(254 - Ee) << 23);                    \
        vv0 *= scl; vv1 *= scl; vv2 *= scl; vv3 *= scl;                       \
        vv4 *= scl; vv5 *= scl; vv6 *= scl; vv7 *= scl;                       \
    }                                                                         \
    uint2 dw0, dw1;                                                           \
    dw0.x = pack2bf(vv0, vv1); dw0.y = pack2bf(vv2, vv3);                     \
    dw1.x = pack2bf(vv4, vv5); dw1.y = pack2bf(vv6, vv7);                     \
    *(uint2*)((WDST) + woff0) = dw0;                                          \
    *(uint2*)((WDST) + woff1) = dw1;                                          \
    __syncthreads();                                                          \
} while (0)

__global__ __launch_bounds__(256) void crf_scan_kernel(
    const float* __restrict__ emit,    // (512,256,128)
    const float* __restrict__ Tm,      // (128,128)
    float*       __restrict__ scan_part) // (256) per-batch log_z
{
    const int gb  = blockIdx.x;       // batch group 0..15
    const int tid = threadIdx.x;
    const int w   = tid >> 6;         // wave 0..3 (owns j in [32w, 32w+32))
    const int l   = tid & 63;
    const int b   = l & 15;           // batch within group / N index / A m index
    const int g   = l >> 4;           // 16-lane group
    const int bg  = gb * 16 + b;      // global batch

    __shared__ __align__(16) unsigned short Wb0[16][128];  // bf16 w[b][i], swizzled
    __shared__ __align__(16) unsigned short Wb1[16][128];
    __shared__ float red[4];
    __shared__ float colsum[4][16];

    // ---- A fragments (constant): A[m][k], m = l&15, k = 8g+e (+32c) ----
    // A = E^T: Et[j][i] = exp(T[i][j]); j = 16*(2w+mt') + (l&15), i = k.
    u32x4 af00, af01, af02, af03, af10, af11, af12, af13;
    {
        const int jA0 = 16 * (2 * w + 0) + b;
        const int jA1 = 16 * (2 * w + 1) + b;
#pragma unroll
        for (int c = 0; c < 4; ++c) {
            u32x4 v0q, v1q;
#pragma unroll
            for (int p = 0; p < 4; ++p) {
                const int i0 = 8 * g + 32 * c + 2 * p;
                float a0 = __builtin_amdgcn_exp2f(Tm[(i0    ) * 128 + jA0] * LOG2E);
                float a1 = __builtin_amdgcn_exp2f(Tm[(i0 + 1) * 128 + jA0] * LOG2E);
                float c0 = __builtin_amdgcn_exp2f(Tm[(i0    ) * 128 + jA1] * LOG2E);
                float c1 = __builtin_amdgcn_exp2f(Tm[(i0 + 1) * 128 + jA1] * LOG2E);
                v0q[p] = pack2bf(a0, a1);
                v1q[p] = pack2bf(c0, c1);
            }
            if (c == 0) { af00 = v0q; af10 = v1q; }
            if (c == 1) { af01 = v0q; af11 = v1q; }
            if (c == 2) { af02 = v0q; af12 = v1q; }
            if (c == 3) { af03 = v0q; af13 = v1q; }
        }
    }

    // ---- constant LDS byte offsets (16B-block XOR swizzle by b&7) ----
    const int bsw   = b & 7;
    const int roff0 = b * 256 + (((g + 0 ) ^ bsw) << 4);
    const int roff1 = b * 256 + (((g + 4 ) ^ bsw) << 4);
    const int roff2 = b * 256 + (((g + 8 ) ^ bsw) << 4);
    const int roff3 = b * 256 + (((g + 12) ^ bsw) << 4);
    const int woff0 = b * 256 + ((((4 * w + 0) + (g >> 1)) ^ bsw) << 4) + 8 * (g & 1);
    const int woff1 = b * 256 + ((((4 * w + 2) + (g >> 1)) ^ bsw) << 4) + 8 * (g & 1);

    char* wb0 = (char*)&Wb0[0][0];
    char* wb1 = (char*)&Wb1[0][0];

    // lane's emit slice base: j = 32w + 4g + q (tile0), +16 (tile1); t stride 32768
    const float* ebase = emit + (size_t)bg * 128 + 32 * w + 4 * g;

    int ls2 = 0;
    float vv0, vv1, vv2, vv3, vv4, vv5, vv6, vv7;

    // ---- t = 0 init: w0[b][j] = exp(emit[0][b][j]) ----
    {
        float4 e0 = *(const float4*)(ebase);
        float4 e1 = *(const float4*)(ebase + 16);
        uint2 dw0, dw1;
        dw0.x = pack2bf(__builtin_amdgcn_exp2f(e0.x * LOG2E),
                        __builtin_amdgcn_exp2f(e0.y * LOG2E));
        dw0.y = pack2bf(__builtin_amdgcn_exp2f(e0.z * LOG2E),
                        __builtin_amdgcn_exp2f(e0.w * LOG2E));
        dw1.x = pack2bf(__builtin_amdgcn_exp2f(e1.x * LOG2E),
                        __builtin_amdgcn_exp2f(e1.y * LOG2E));
        dw1.y = pack2bf(__builtin_amdgcn_exp2f(e1.z * LOG2E),
                        __builtin_amdgcn_exp2f(e1.w * LOG2E));
        *(uint2*)(wb0 + woff0) = dw0;
        *(uint2*)(wb0 + woff1) = dw1;
    }
    __syncthreads();

    // ---- prefetch emit for t = 1..4 ----
    float4 pA00 = *(const float4*)(ebase + (size_t)1 * 32768);
    float4 pA01 = *(const float4*)(ebase + (size_t)1 * 32768 + 16);
    float4 pA10 = *(const float4*)(ebase + (size_t)2 * 32768);
    float4 pA11 = *(const float4*)(ebase + (size_t)2 * 32768 + 16);
    float4 pA20 = *(const float4*)(ebase + (size_t)3 * 32768);
    float4 pA21 = *(const float4*)(ebase + (size_t)3 * 32768 + 16);
    float4 pA30 = *(const float4*)(ebase + (size_t)4 * 32768);
    float4 pA31 = *(const float4*)(ebase + (size_t)4 * 32768 + 16);

    // ---- main loop: t = 1..508, renorm on every 4th step ----
#pragma unroll 1
    for (int grp = 0; grp < 127; ++grp) {
        const int t0 = 1 + 4 * grp;
        int t7 = t0 + 7; if (t7 > 511) t7 = 511;
        float4 pB00 = *(const float4*)(ebase + (size_t)(t0 + 4) * 32768);
        float4 pB01 = *(const float4*)(ebase + (size_t)(t0 + 4) * 32768 + 16);
        float4 pB10 = *(const float4*)(ebase + (size_t)(t0 + 5) * 32768);
        float4 pB11 = *(const float4*)(ebase + (size_t)(t0 + 5) * 32768 + 16);
        float4 pB20 = *(const float4*)(ebase + (size_t)(t0 + 6) * 32768);
        float4 pB21 = *(const float4*)(ebase + (size_t)(t0 + 6) * 32768 + 16);
        float4 pB30 = *(const float4*)(ebase + (size_t)t7 * 32768);
        float4 pB31 = *(const float4*)(ebase + (size_t)t7 * 32768 + 16);

        CRF_STEP(pA00, pA01, wb0, wb1, 0);
        CRF_STEP(pA10, pA11, wb1, wb0, 0);
        CRF_STEP(pA20, pA21, wb0, wb1, 0);
        CRF_STEP(pA30, pA31, wb1, wb0, 1);

        pA00 = pB00; pA01 = pB01; pA10 = pB10; pA11 = pB11;
        pA20 = pB20; pA21 = pB21; pA30 = pB30; pA31 = pB31;
    }
    // tail: t = 509, 510, 511 (growth since t=508 renorm fits fp32 easily)
    CRF_STEP(pA00, pA01, wb0, wb1, 0);
    CRF_STEP(pA10, pA11, wb1, wb0, 0);
    CRF_STEP(pA20, pA21, wb0, wb1, 0);

    // ---- finalize: log_z_b = (ls2 + log2(sum_j w[b][j])) * ln2 ----
    float s = ((vv0 + vv1) + (vv2 + vv3)) + ((vv4 + vv5) + (vv6 + vv7));
    s += __shfl_xor(s, 16);
    s += __shfl_xor(s, 32);
    if (l < 16) colsum[w][l] = s;
    __syncthreads();
    if (tid < 16) {
        float tot = (colsum[0][tid] + colsum[1][tid]) +
                    (colsum[2][tid] + colsum[3][tid]);
        scan_part[gb * 16 + tid] = ((float)ls2 + __log2f(tot)) * LN2F;
    }
}

__global__ __launch_bounds__(256) void crf_gold_kernel(
    const float* __restrict__ emit, const float* __restrict__ Tm,
    const int* __restrict__ labels, const int* __restrict__ startp,
    float* __restrict__ gold_part)   // (256)
{
    const int b = blockIdx.x, tid = threadIdx.x;
    __shared__ int lab[512];
    __shared__ float r[4];
    lab[tid]       = labels[b * 512 + tid];
    lab[tid + 256] = labels[b * 512 + tid + 256];
    __syncthreads();
    float s = 0.f;
    {
        int y0 = lab[tid];
        int p0 = (tid == 0) ? startp[0] : lab[tid - 1];
        s += emit[((size_t)tid * 256 + b) * 128 + y0] + Tm[p0 * 128 + y0];
        int t1 = tid + 256;
        int y1 = lab[t1];
        int p1 = lab[t1 - 1];
        s += emit[((size_t)t1 * 256 + b) * 128 + y1] + Tm[p1 * 128 + y1];
    }
#pragma unroll
    for (int off = 1; off < 64; off <<= 1) s += __shfl_xor(s, off);
    if ((tid & 63) == 0) r[tid >> 6] = s;
    __syncthreads();
    if (tid == 0) gold_part[b] = (r[0] + r[1]) + (r[2] + r[3]);
}

__global__ __launch_bounds__(256) void crf_final_kernel(
    const float* __restrict__ scan_part, const float* __restrict__ gold_part,
    float* __restrict__ out)
{
    const int tid = threadIdx.x;
    __shared__ float r[4];
    float v = scan_part[tid] - gold_part[tid];
#pragma unroll
    for (int off = 1; off < 64; off <<= 1) v += __shfl_xor(v, off);
    if ((tid & 63) == 0) r[tid >> 6] = v;
    __syncthreads();
    if (tid == 0) out[0] = (r[0] + r[1]) + (r[2] + r[3]);
}

extern "C" void kernel_launch(void* const* d_in, const int* in_sizes, int n_in,
                              void* d_out, int out_size, void* d_ws, size_t ws_size,
                              hipStream_t stream) {
    const float* emit   = (const float*)d_in[0];
    const float* Tm     = (const float*)d_in[1];
    const int*   labels = (const int*)d_in[2];
    const int*   startp = (const int*)d_in[3];

    float* scan_part = (float*)d_ws;        // 256 floats
    float* gold_part = scan_part + 256;     // 256 floats

    crf_scan_kernel <<<16,  256, 0, stream>>>(emit, Tm, scan_part);
    crf_gold_kernel <<<256, 256, 0, stream>>>(emit, Tm, labels, startp, gold_part);
    crf_final_kernel<<<1,   256, 0, stream>>>(scan_part, gold_part, (float*)d_out);
}